// Round 3
// baseline (13307.156 us; speedup 1.0000x reference)
//
#include <hip/hip_runtime.h>
#include <math.h>

#define N_NODES 200000
#define H_CH    128
#define GRP     64          // channel group width (2 groups of 64)
#define NNZ_E   3200000
#define K_DEG   15

// bucketed CSR build parameters
#define EPB     4096        // edges per block in bucket pass A
#define BSHIFT  9           // 512 rows per bucket
#define BROWS   512
#define NBUCK   391         // ceil(200000 / 512)
#define BCAP    9216        // per-bucket staging capacity (mean 8192, +11 sigma)

// persistent kernel geometry: 768 blocks = 3 blocks/CU (slack vs 4/CU capacity
// at <=128 VGPR, so all blocks are guaranteed co-resident -> no barrier deadlock)
#define PBLK    768
#define PWAVES  (PBLK * 4)  // 3072 waves
#define RPW     66          // rows per wave: ceil(200000 / 3072)

// ---------- softmax over 16 logits ----------
__global__ void softmax_k(const float* __restrict__ logits, float* __restrict__ w) {
    if (threadIdx.x == 0) {
        float m = -1e30f;
        for (int i = 0; i <= K_DEG; ++i) m = fmaxf(m, logits[i]);
        float e[K_DEG + 1];
        float s = 0.f;
        for (int i = 0; i <= K_DEG; ++i) { e[i] = expf(logits[i] - m); s += e[i]; }
        float inv = 1.0f / s;
        for (int i = 0; i <= K_DEG; ++i) w[i] = e[i] * inv;
    }
}

// ---------- bucket pass A: block-local LDS binning by row bucket ----------
__global__ __launch_bounds__(256) void bucketA_k(
    const int* __restrict__ row, const int* __restrict__ col,
    const float* __restrict__ vals,
    int* __restrict__ gfill, uint2* __restrict__ stag, int nnz) {
    __shared__ int cnt[NBUCK];
    __shared__ int excl[NBUCK];
    __shared__ int gbase[NBUCK];
    __shared__ int sm[256];
    __shared__ uint2 sstag[EPB];
    __shared__ unsigned short sb[EPB];

    int tid = threadIdx.x;
    int base = blockIdx.x * EPB;

    for (int t = tid; t < NBUCK; t += 256) cnt[t] = 0;
    __syncthreads();

    int r[16], c[16], b[16];
    float v[16];
#pragma unroll
    for (int j = 0; j < 16; ++j) {
        int i = base + j * 256 + tid;
        if (i < nnz) {
            r[j] = row[i]; c[j] = col[i]; v[j] = vals[i];
            b[j] = r[j] >> BSHIFT;
            atomicAdd(&cnt[b[j]], 1);
        } else {
            b[j] = -1;
        }
    }
    __syncthreads();

    {
        int b0 = 2 * tid, b1 = 2 * tid + 1;
        int c0 = (b0 < NBUCK) ? cnt[b0] : 0;
        int c1 = (b1 < NBUCK) ? cnt[b1] : 0;
        int pair = c0 + c1;
        sm[tid] = pair;
        __syncthreads();
        int incl = pair;
        for (int off = 1; off < 256; off <<= 1) {
            int tv = (tid >= off) ? sm[tid - off] : 0;
            __syncthreads();
            incl += tv;
            sm[tid] = incl;
            __syncthreads();
        }
        int pexcl = incl - pair;
        if (b0 < NBUCK) excl[b0] = pexcl;
        if (b1 < NBUCK) excl[b1] = pexcl + c0;
    }
    __syncthreads();

    for (int t = tid; t < NBUCK; t += 256) {
        int cb = cnt[t];
        gbase[t] = (cb > 0) ? atomicAdd(&gfill[t], cb) : 0;
    }
    __syncthreads();
    for (int t = tid; t < NBUCK; t += 256) cnt[t] = excl[t];
    __syncthreads();

#pragma unroll
    for (int j = 0; j < 16; ++j) {
        if (b[j] >= 0) {
            int p = atomicAdd(&cnt[b[j]], 1);
            sstag[p] = make_uint2(((unsigned)(r[j] & 511) << 18) | (unsigned)c[j],
                                  __float_as_uint(v[j]));
            sb[p] = (unsigned short)b[j];
        }
    }
    __syncthreads();

    int tot = nnz - base; if (tot > EPB) tot = EPB;
    for (int i = tid; i < tot; i += 256) {
        int bb = sb[i];
        size_t gp = (size_t)bb * BCAP + gbase[bb] + (i - excl[bb]);
        stag[gp] = sstag[i];
    }
}

// ---------- tiny scan over 391 bucket totals ----------
__global__ void scanG_k(const int* __restrict__ gfill, int* __restrict__ bbase,
                        int* __restrict__ row_ptr) {
    __shared__ int sm[256];
    int tid = threadIdx.x;
    int j0 = 2 * tid, j1 = 2 * tid + 1;
    int c0 = (j0 < NBUCK) ? gfill[j0] : 0;
    int c1 = (j1 < NBUCK) ? gfill[j1] : 0;
    int pair = c0 + c1;
    sm[tid] = pair;
    __syncthreads();
    int incl = pair;
    for (int off = 1; off < 256; off <<= 1) {
        int t = (tid >= off) ? sm[tid - off] : 0;
        __syncthreads();
        incl += t;
        sm[tid] = incl;
        __syncthreads();
    }
    int pexcl = incl - pair;
    if (j0 < NBUCK) bbase[j0] = pexcl;
    if (j1 < NBUCK) bbase[j1] = pexcl + c0;
    if (tid == 0) row_ptr[N_NODES] = NNZ_E;
}

// ---------- bucket pass B: bucket-local CSR build ----------
__global__ __launch_bounds__(256) void bucketB_k(
    const uint2* __restrict__ stag, const int* __restrict__ gfill,
    const int* __restrict__ bbase, int* __restrict__ row_ptr,
    int2* __restrict__ csr) {
    __shared__ int hist[BROWS];
    __shared__ int lexcl[BROWS];
    __shared__ int sm[256];
    int b = blockIdx.x;
    int n = gfill[b];
    int cs = bbase[b];
    const uint2* s = stag + (size_t)b * BCAP;
    int tid = threadIdx.x;

    hist[tid] = 0; hist[tid + 256] = 0;
    __syncthreads();
    for (int i = tid; i < n; i += 256)
        atomicAdd(&hist[s[i].x >> 18], 1);
    __syncthreads();

    int j0 = 2 * tid, j1 = 2 * tid + 1;
    int c0 = hist[j0], c1 = hist[j1];
    int pair = c0 + c1;
    sm[tid] = pair;
    __syncthreads();
    int incl = pair;
    for (int off = 1; off < 256; off <<= 1) {
        int t = (tid >= off) ? sm[tid - off] : 0;
        __syncthreads();
        incl += t;
        sm[tid] = incl;
        __syncthreads();
    }
    int pexcl = incl - pair;
    lexcl[j0] = pexcl;
    lexcl[j1] = pexcl + c0;

    int rbase = b << BSHIFT;
    if (rbase + j0 < N_NODES) row_ptr[rbase + j0] = cs + lexcl[j0];
    if (rbase + j1 < N_NODES) row_ptr[rbase + j1] = cs + lexcl[j1];
    hist[j0] = lexcl[j0];
    hist[j1] = lexcl[j1];
    __syncthreads();

    for (int i = tid; i < n; i += 256) {
        uint2 e = s[i];
        int rl = (int)(e.x >> 18);
        int p = cs + atomicAdd(&hist[rl], 1);
        int2 cv;
        cv.x = (int)(e.x & 0x3FFFF);
        cv.y = (int)e.y;
        csr[p] = cv;
    }
}

// ---------- device-scope grid barrier (all PBLK blocks co-resident) ----------
// tid0's release-add flushes the XCD L2 (this block's stores were already
// drained to L2 by __syncthreads' vmcnt wait); the post-spin __threadfence
// does the agent-scope L1+L2 invalidate so subsequent gathers see all XCDs.
__device__ __forceinline__ void gsync(int* cnt, int target) {
    __syncthreads();
    if (threadIdx.x == 0) {
        __hip_atomic_fetch_add(cnt, 1, __ATOMIC_RELEASE, __HIP_MEMORY_SCOPE_AGENT);
        while (__hip_atomic_load(cnt, __ATOMIC_RELAXED, __HIP_MEMORY_SCOPE_AGENT) < target)
            __builtin_amdgcn_s_sleep(2);
        __threadfence();
    }
    __syncthreads();
}

// ---------- persistent fused polynomial kernel ----------
// Each wave owns RPW rows (row = wv + PWAVES*j); the out accumulator lives in
// registers across all K steps -> deletes the per-step out RMW (102.4 MB/step
// of EA traffic). T ping-pongs through bufA/bufB in global (needed for gathers).
__global__ __launch_bounds__(256, 4) void poly_k(
    const int* __restrict__ rp, const int2* __restrict__ csr,
    const float* __restrict__ x, float* __restrict__ bufA,
    float* __restrict__ bufB, float* __restrict__ out,
    const float* __restrict__ w, const float* __restrict__ alpha_p,
    int* __restrict__ barcnt) {
    const int tid = threadIdx.x;
    const int wv = __builtin_amdgcn_readfirstlane(blockIdx.x * 4 + (tid >> 6));
    const int lane = tid & 63;
    const float w0 = w[0], w1 = w[1], al = alpha_p[0];
    float oa[RPW];
    int gen = 0;

    for (int g = 0; g < 2; ++g) {
        const int goff = g << 6;

        // ---- phase 1: S = spmm(x); T1 = S - x; oa = -(w0 x + w1 T1) + al(x - S/2)
#pragma unroll
        for (int j = 0; j < RPW; ++j) {
            const int r = wv + PWAVES * j;
            if (r < N_NODES) {
                const float* gb = x + goff + lane;
                const int e0 = rp[r], e1 = rp[r + 1];
                float a0 = 0.f, a1 = 0.f, a2 = 0.f, a3 = 0.f;
                int e = e0;
                for (; e + 4 <= e1; e += 4) {
                    int2 c0 = csr[e], c1 = csr[e + 1], c2 = csr[e + 2], c3 = csr[e + 3];
                    a0 = fmaf(__int_as_float(c0.y), gb[(unsigned)c0.x * H_CH], a0);
                    a1 = fmaf(__int_as_float(c1.y), gb[(unsigned)c1.x * H_CH], a1);
                    a2 = fmaf(__int_as_float(c2.y), gb[(unsigned)c2.x * H_CH], a2);
                    a3 = fmaf(__int_as_float(c3.y), gb[(unsigned)c3.x * H_CH], a3);
                }
                for (; e < e1; ++e) {
                    int2 cv = csr[e];
                    a0 = fmaf(__int_as_float(cv.y), gb[(unsigned)cv.x * H_CH], a0);
                }
                float s = (a0 + a1) + (a2 + a3);
                float xr = x[(unsigned)r * H_CH + goff + lane];
                float t1 = s - xr;
                bufB[(unsigned)r * GRP + lane] = t1;
                oa[j] = -(w0 * xr + w1 * t1) + al * (xr - 0.5f * s);
            }
        }
        gsync(barcnt, (++gen) * PBLK);

        // ---- k = 2..15: Tn = 2(spmm(Tc) - Tc) - Tp; oa -= w[k]*Tn
        for (int k = 2; k <= K_DEG; ++k) {
            const float* Tc = (k & 1) ? bufA : bufB;   // k=2 reads T1 in bufB
            float* Tn = (k & 1) ? bufB : bufA;         // Tnext aliases Tprev
            const float wk = w[k];
#pragma unroll
            for (int j = 0; j < RPW; ++j) {
                const int r = wv + PWAVES * j;
                if (r < N_NODES) {
                    const float* gb = Tc + lane;
                    const int e0 = rp[r], e1 = rp[r + 1];
                    float a0 = 0.f, a1 = 0.f, a2 = 0.f, a3 = 0.f;
                    int e = e0;
                    for (; e + 4 <= e1; e += 4) {
                        int2 c0 = csr[e], c1 = csr[e + 1], c2 = csr[e + 2], c3 = csr[e + 3];
                        a0 = fmaf(__int_as_float(c0.y), gb[(unsigned)c0.x * GRP], a0);
                        a1 = fmaf(__int_as_float(c1.y), gb[(unsigned)c1.x * GRP], a1);
                        a2 = fmaf(__int_as_float(c2.y), gb[(unsigned)c2.x * GRP], a2);
                        a3 = fmaf(__int_as_float(c3.y), gb[(unsigned)c3.x * GRP], a3);
                    }
                    for (; e < e1; ++e) {
                        int2 cv = csr[e];
                        a0 = fmaf(__int_as_float(cv.y), gb[(unsigned)cv.x * GRP], a0);
                    }
                    float s = (a0 + a1) + (a2 + a3);
                    const unsigned idxg = (unsigned)r * GRP + lane;
                    float tc = Tc[idxg];
                    float tp = (k == 2) ? x[(unsigned)r * H_CH + goff + lane]
                                        : Tn[idxg];    // own row: read-before-write
                    float tn = 2.0f * (s - tc) - tp;
                    Tn[idxg] = tn;
                    oa[j] -= wk * tn;
                }
            }
            gsync(barcnt, (++gen) * PBLK);
        }

        // ---- final store of this group's out slice
#pragma unroll
        for (int j = 0; j < RPW; ++j) {
            const int r = wv + PWAVES * j;
            if (r < N_NODES) out[(unsigned)r * H_CH + goff + lane] = oa[j];
        }
        // no extra sync needed: k=15's gsync ordered all T writes; g=1 phase-1
        // writes only its own rows of bufB (no cross-row access before its sync)
    }
}

extern "C" void kernel_launch(void* const* d_in, const int* in_sizes, int n_in,
                              void* d_out, int out_size, void* d_ws, size_t ws_size,
                              hipStream_t stream) {
    const float* x      = (const float*)d_in[0];
    const float* vals   = (const float*)d_in[1];
    const float* logits = (const float*)d_in[2];
    const float* alpha  = (const float*)d_in[3];
    const int*   erow   = (const int*)d_in[4];
    const int*   ecol   = (const int*)d_in[5];
    float* out = (float*)d_out;

    const size_t NG = (size_t)N_NODES * GRP;
    float* bufA    = (float*)d_ws;                 // N x 64
    float* bufB    = bufA + NG;                    // N x 64
    int2*  csr     = (int2*)(bufB + NG);           // packed col+val, NNZ
    uint2* stag    = (uint2*)(csr + NNZ_E);        // bucket staging
    int*   row_ptr = (int*)(stag + (size_t)NBUCK * BCAP);  // N+1
    int*   gfill   = row_ptr + (N_NODES + 1);      // NBUCK
    int*   bbase   = gfill + NBUCK;                // NBUCK
    float* w_buf   = (float*)(bbase + NBUCK);      // 16
    int*   barcnt  = (int*)(w_buf + 16);           // 1

    hipMemsetAsync(gfill, 0, NBUCK * sizeof(int), stream);
    hipMemsetAsync(barcnt, 0, sizeof(int), stream);
    softmax_k<<<1, 64, 0, stream>>>(logits, w_buf);

    int nblkA = (NNZ_E + EPB - 1) / EPB;
    bucketA_k<<<nblkA, 256, 0, stream>>>(erow, ecol, vals, gfill, stag, NNZ_E);
    scanG_k<<<1, 256, 0, stream>>>(gfill, bbase, row_ptr);
    bucketB_k<<<NBUCK, 256, 0, stream>>>(stag, gfill, bbase, row_ptr, csr);

    poly_k<<<PBLK, 256, 0, stream>>>(row_ptr, csr, x, bufA, bufB, out,
                                     w_buf, alpha, barcnt);
}

// Round 4
// 4392.842 us; speedup vs baseline: 3.0293x; 3.0293x over previous
//
#include <hip/hip_runtime.h>
#include <math.h>

#define N_NODES 200000
#define H_CH    128
#define GRP     64          // channel group width (2 groups of 64)
#define NNZ_E   3200000
#define K_DEG   15

// bucketed CSR build parameters
#define EPB     4096        // edges per block in bucket pass A
#define BSHIFT  9           // 512 rows per bucket
#define BROWS   512
#define NBUCK   391         // ceil(200000 / 512)
#define BCAP    9216        // per-bucket staging capacity (mean 8192, +11 sigma)

// ---------- softmax over 16 logits ----------
__global__ void softmax_k(const float* __restrict__ logits, float* __restrict__ w) {
    if (threadIdx.x == 0) {
        float m = -1e30f;
        for (int i = 0; i <= K_DEG; ++i) m = fmaxf(m, logits[i]);
        float e[K_DEG + 1];
        float s = 0.f;
        for (int i = 0; i <= K_DEG; ++i) { e[i] = expf(logits[i] - m); s += e[i]; }
        float inv = 1.0f / s;
        for (int i = 0; i <= K_DEG; ++i) w[i] = e[i] * inv;
    }
}

// ---------- bucket pass A: block-local LDS binning by row bucket ----------
__global__ __launch_bounds__(256) void bucketA_k(
    const int* __restrict__ row, const int* __restrict__ col,
    const float* __restrict__ vals,
    int* __restrict__ gfill, uint2* __restrict__ stag, int nnz) {
    __shared__ int cnt[NBUCK];
    __shared__ int excl[NBUCK];
    __shared__ int gbase[NBUCK];
    __shared__ int sm[256];
    __shared__ uint2 sstag[EPB];
    __shared__ unsigned short sb[EPB];

    int tid = threadIdx.x;
    int base = blockIdx.x * EPB;

    for (int t = tid; t < NBUCK; t += 256) cnt[t] = 0;
    __syncthreads();

    int r[16], c[16], b[16];
    float v[16];
#pragma unroll
    for (int j = 0; j < 16; ++j) {
        int i = base + j * 256 + tid;
        if (i < nnz) {
            r[j] = row[i]; c[j] = col[i]; v[j] = vals[i];
            b[j] = r[j] >> BSHIFT;
            atomicAdd(&cnt[b[j]], 1);
        } else {
            b[j] = -1;
        }
    }
    __syncthreads();

    {
        int b0 = 2 * tid, b1 = 2 * tid + 1;
        int c0 = (b0 < NBUCK) ? cnt[b0] : 0;
        int c1 = (b1 < NBUCK) ? cnt[b1] : 0;
        int pair = c0 + c1;
        sm[tid] = pair;
        __syncthreads();
        int incl = pair;
        for (int off = 1; off < 256; off <<= 1) {
            int tv = (tid >= off) ? sm[tid - off] : 0;
            __syncthreads();
            incl += tv;
            sm[tid] = incl;
            __syncthreads();
        }
        int pexcl = incl - pair;
        if (b0 < NBUCK) excl[b0] = pexcl;
        if (b1 < NBUCK) excl[b1] = pexcl + c0;
    }
    __syncthreads();

    for (int t = tid; t < NBUCK; t += 256) {
        int cb = cnt[t];
        gbase[t] = (cb > 0) ? atomicAdd(&gfill[t], cb) : 0;
    }
    __syncthreads();
    for (int t = tid; t < NBUCK; t += 256) cnt[t] = excl[t];
    __syncthreads();

#pragma unroll
    for (int j = 0; j < 16; ++j) {
        if (b[j] >= 0) {
            int p = atomicAdd(&cnt[b[j]], 1);
            sstag[p] = make_uint2(((unsigned)(r[j] & 511) << 18) | (unsigned)c[j],
                                  __float_as_uint(v[j]));
            sb[p] = (unsigned short)b[j];
        }
    }
    __syncthreads();

    int tot = nnz - base; if (tot > EPB) tot = EPB;
    for (int i = tid; i < tot; i += 256) {
        int bb = sb[i];
        size_t gp = (size_t)bb * BCAP + gbase[bb] + (i - excl[bb]);
        stag[gp] = sstag[i];
    }
}

// ---------- tiny scan over 391 bucket totals ----------
__global__ void scanG_k(const int* __restrict__ gfill, int* __restrict__ bbase,
                        int* __restrict__ row_ptr) {
    __shared__ int sm[256];
    int tid = threadIdx.x;
    int j0 = 2 * tid, j1 = 2 * tid + 1;
    int c0 = (j0 < NBUCK) ? gfill[j0] : 0;
    int c1 = (j1 < NBUCK) ? gfill[j1] : 0;
    int pair = c0 + c1;
    sm[tid] = pair;
    __syncthreads();
    int incl = pair;
    for (int off = 1; off < 256; off <<= 1) {
        int t = (tid >= off) ? sm[tid - off] : 0;
        __syncthreads();
        incl += t;
        sm[tid] = incl;
        __syncthreads();
    }
    int pexcl = incl - pair;
    if (j0 < NBUCK) bbase[j0] = pexcl;
    if (j1 < NBUCK) bbase[j1] = pexcl + c0;
    if (tid == 0) row_ptr[N_NODES] = NNZ_E;
}

// ---------- bucket pass B: bucket-local CSR build ----------
__global__ __launch_bounds__(256) void bucketB_k(
    const uint2* __restrict__ stag, const int* __restrict__ gfill,
    const int* __restrict__ bbase, int* __restrict__ row_ptr,
    int2* __restrict__ csr) {
    __shared__ int hist[BROWS];
    __shared__ int lexcl[BROWS];
    __shared__ int sm[256];
    int b = blockIdx.x;
    int n = gfill[b];
    int cs = bbase[b];
    const uint2* s = stag + (size_t)b * BCAP;
    int tid = threadIdx.x;

    hist[tid] = 0; hist[tid + 256] = 0;
    __syncthreads();
    for (int i = tid; i < n; i += 256)
        atomicAdd(&hist[s[i].x >> 18], 1);
    __syncthreads();

    int j0 = 2 * tid, j1 = 2 * tid + 1;
    int c0 = hist[j0], c1 = hist[j1];
    int pair = c0 + c1;
    sm[tid] = pair;
    __syncthreads();
    int incl = pair;
    for (int off = 1; off < 256; off <<= 1) {
        int t = (tid >= off) ? sm[tid - off] : 0;
        __syncthreads();
        incl += t;
        sm[tid] = incl;
        __syncthreads();
    }
    int pexcl = incl - pair;
    lexcl[j0] = pexcl;
    lexcl[j1] = pexcl + c0;

    int rbase = b << BSHIFT;
    if (rbase + j0 < N_NODES) row_ptr[rbase + j0] = cs + lexcl[j0];
    if (rbase + j1 < N_NODES) row_ptr[rbase + j1] = cs + lexcl[j1];
    hist[j0] = lexcl[j0];
    hist[j1] = lexcl[j1];
    __syncthreads();

    for (int i = tid; i < n; i += 256) {
        uint2 e = s[i];
        int rl = (int)(e.x >> 18);
        int p = cs + atomicAdd(&hist[rl], 1);
        int2 cv;
        cv.x = (int)(e.x & 0x3FFFF);
        cv.y = (int)e.y;
        csr[p] = cv;
    }
}

// ---------- first fused kernel (per 64-ch group), 8-wide edge unroll ----------
// S = spmm(x_g); T1_g = S - x_g; out_g = -(w0*x_g + w1*T1_g) + alpha*(x_g - 0.5*S)
// 8 independent gathers in flight per wave (loop is latency-bound: Round-3
// showed effective BW scales ~linearly with outstanding loads).
__global__ __launch_bounds__(512) void first_k(
    const int* __restrict__ rp, const int2* __restrict__ csr,
    const float* __restrict__ x, float* __restrict__ T1g, float* __restrict__ out,
    const float* __restrict__ w, const float* __restrict__ alpha_p, int goff) {
    int wid = blockIdx.x * 8 + (threadIdx.x >> 6);
    int r = __builtin_amdgcn_readfirstlane(wid);
    if (r >= N_NODES) return;
    int lane = threadIdx.x & 63;
    const float* base = x + goff + lane;      // gather x[col*128 + goff + lane]
    int e0 = rp[r], e1 = rp[r + 1];
    float a0 = 0.f, a1 = 0.f, a2 = 0.f, a3 = 0.f;
    float a4 = 0.f, a5 = 0.f, a6 = 0.f, a7 = 0.f;
    int e = e0;
    for (; e + 8 <= e1; e += 8) {
        int2 cv0 = csr[e],     cv1 = csr[e + 1], cv2 = csr[e + 2], cv3 = csr[e + 3];
        int2 cv4 = csr[e + 4], cv5 = csr[e + 5], cv6 = csr[e + 6], cv7 = csr[e + 7];
        a0 = fmaf(__int_as_float(cv0.y), base[(unsigned)cv0.x * H_CH], a0);
        a1 = fmaf(__int_as_float(cv1.y), base[(unsigned)cv1.x * H_CH], a1);
        a2 = fmaf(__int_as_float(cv2.y), base[(unsigned)cv2.x * H_CH], a2);
        a3 = fmaf(__int_as_float(cv3.y), base[(unsigned)cv3.x * H_CH], a3);
        a4 = fmaf(__int_as_float(cv4.y), base[(unsigned)cv4.x * H_CH], a4);
        a5 = fmaf(__int_as_float(cv5.y), base[(unsigned)cv5.x * H_CH], a5);
        a6 = fmaf(__int_as_float(cv6.y), base[(unsigned)cv6.x * H_CH], a6);
        a7 = fmaf(__int_as_float(cv7.y), base[(unsigned)cv7.x * H_CH], a7);
    }
    for (; e + 4 <= e1; e += 4) {
        int2 cv0 = csr[e], cv1 = csr[e + 1], cv2 = csr[e + 2], cv3 = csr[e + 3];
        a0 = fmaf(__int_as_float(cv0.y), base[(unsigned)cv0.x * H_CH], a0);
        a1 = fmaf(__int_as_float(cv1.y), base[(unsigned)cv1.x * H_CH], a1);
        a2 = fmaf(__int_as_float(cv2.y), base[(unsigned)cv2.x * H_CH], a2);
        a3 = fmaf(__int_as_float(cv3.y), base[(unsigned)cv3.x * H_CH], a3);
    }
    for (; e < e1; ++e) {
        int2 cv = csr[e];
        a0 = fmaf(__int_as_float(cv.y), base[(unsigned)cv.x * H_CH], a0);
    }
    float s = ((a0 + a1) + (a2 + a3)) + ((a4 + a5) + (a6 + a7));
    size_t idxg = (size_t)r * GRP + lane;
    size_t idxf = (size_t)r * H_CH + goff + lane;
    float xr = x[idxf];
    float w0 = w[0], w1 = w[1], al = alpha_p[0];
    float t1 = s - xr;
    float o = -(w0 * xr + w1 * t1) + al * (xr - 0.5f * s);
    T1g[idxg] = t1;
    out[idxf] = o;
}

// ---------- Chebyshev step (per 64-ch group), 8-wide edge unroll ----------
// y = spmm(Tcur); Tn = 2*(y - Tcur) - Tprev; out -= w[k]*Tn; Tnext = Tn
__global__ __launch_bounds__(512) void cheb_k(
    const int* __restrict__ rp, const int2* __restrict__ csr,
    const float* __restrict__ Tcur, const float* TprevBase, int tprevStride,
    float* Tnext, float* __restrict__ out,
    const float* __restrict__ w, int k, int goff) {
    int wid = blockIdx.x * 8 + (threadIdx.x >> 6);
    int r = __builtin_amdgcn_readfirstlane(wid);
    if (r >= N_NODES) return;
    int lane = threadIdx.x & 63;
    const float* base = Tcur + lane;          // gather Tcur[col*64 + lane]
    int e0 = rp[r], e1 = rp[r + 1];
    float a0 = 0.f, a1 = 0.f, a2 = 0.f, a3 = 0.f;
    float a4 = 0.f, a5 = 0.f, a6 = 0.f, a7 = 0.f;
    int e = e0;
    for (; e + 8 <= e1; e += 8) {
        int2 cv0 = csr[e],     cv1 = csr[e + 1], cv2 = csr[e + 2], cv3 = csr[e + 3];
        int2 cv4 = csr[e + 4], cv5 = csr[e + 5], cv6 = csr[e + 6], cv7 = csr[e + 7];
        a0 = fmaf(__int_as_float(cv0.y), base[(unsigned)cv0.x * GRP], a0);
        a1 = fmaf(__int_as_float(cv1.y), base[(unsigned)cv1.x * GRP], a1);
        a2 = fmaf(__int_as_float(cv2.y), base[(unsigned)cv2.x * GRP], a2);
        a3 = fmaf(__int_as_float(cv3.y), base[(unsigned)cv3.x * GRP], a3);
        a4 = fmaf(__int_as_float(cv4.y), base[(unsigned)cv4.x * GRP], a4);
        a5 = fmaf(__int_as_float(cv5.y), base[(unsigned)cv5.x * GRP], a5);
        a6 = fmaf(__int_as_float(cv6.y), base[(unsigned)cv6.x * GRP], a6);
        a7 = fmaf(__int_as_float(cv7.y), base[(unsigned)cv7.x * GRP], a7);
    }
    for (; e + 4 <= e1; e += 4) {
        int2 cv0 = csr[e], cv1 = csr[e + 1], cv2 = csr[e + 2], cv3 = csr[e + 3];
        a0 = fmaf(__int_as_float(cv0.y), base[(unsigned)cv0.x * GRP], a0);
        a1 = fmaf(__int_as_float(cv1.y), base[(unsigned)cv1.x * GRP], a1);
        a2 = fmaf(__int_as_float(cv2.y), base[(unsigned)cv2.x * GRP], a2);
        a3 = fmaf(__int_as_float(cv3.y), base[(unsigned)cv3.x * GRP], a3);
    }
    for (; e < e1; ++e) {
        int2 cv = csr[e];
        a0 = fmaf(__int_as_float(cv.y), base[(unsigned)cv.x * GRP], a0);
    }
    float s = ((a0 + a1) + (a2 + a3)) + ((a4 + a5) + (a6 + a7));
    size_t idxg = (size_t)r * GRP + lane;
    size_t idxf = (size_t)r * H_CH + goff + lane;
    float tc = Tcur[idxg];
    float tp = TprevBase[(size_t)r * tprevStride + lane];
    float wk = w[k];
    float tn = 2.0f * (s - tc) - tp;
    float o = out[idxf];
    o -= wk * tn;
    out[idxf] = o;
    Tnext[idxg] = tn;
}

extern "C" void kernel_launch(void* const* d_in, const int* in_sizes, int n_in,
                              void* d_out, int out_size, void* d_ws, size_t ws_size,
                              hipStream_t stream) {
    const float* x      = (const float*)d_in[0];
    const float* vals   = (const float*)d_in[1];
    const float* logits = (const float*)d_in[2];
    const float* alpha  = (const float*)d_in[3];
    const int*   erow   = (const int*)d_in[4];
    const int*   ecol   = (const int*)d_in[5];
    float* out = (float*)d_out;

    const size_t NG = (size_t)N_NODES * GRP;
    float* bufA    = (float*)d_ws;                 // N x 64
    float* bufB    = bufA + NG;                    // N x 64
    int2*  csr     = (int2*)(bufB + NG);           // packed col+val, NNZ
    uint2* stag    = (uint2*)(csr + NNZ_E);        // bucket staging
    int*   row_ptr = (int*)(stag + (size_t)NBUCK * BCAP);  // N+1
    int*   gfill   = row_ptr + (N_NODES + 1);      // NBUCK
    int*   bbase   = gfill + NBUCK;                // NBUCK
    float* w_buf   = (float*)(bbase + NBUCK);      // 16

    hipMemsetAsync(gfill, 0, NBUCK * sizeof(int), stream);
    softmax_k<<<1, 64, 0, stream>>>(logits, w_buf);

    int nblkA = (NNZ_E + EPB - 1) / EPB;
    bucketA_k<<<nblkA, 256, 0, stream>>>(erow, ecol, vals, gfill, stag, NNZ_E);
    scanG_k<<<1, 256, 0, stream>>>(gfill, bbase, row_ptr);
    bucketB_k<<<NBUCK, 256, 0, stream>>>(stag, gfill, bbase, row_ptr, csr);

    int grid = (N_NODES + 7) / 8;                  // 8 rows (waves) per 512-thread block

    for (int g = 0; g < H_CH / GRP; ++g) {
        int goff = g * GRP;
        first_k<<<grid, 512, 0, stream>>>(row_ptr, csr, x, bufB, out, w_buf, alpha, goff);
        cheb_k<<<grid, 512, 0, stream>>>(row_ptr, csr, bufB, x + goff, H_CH, bufA,
                                         out, w_buf, 2, goff);
        float* Tcur = bufA;
        float* Tprev = bufB;
        for (int k = 3; k <= K_DEG; ++k) {
            cheb_k<<<grid, 512, 0, stream>>>(row_ptr, csr, Tcur, Tprev, GRP, Tprev,
                                             out, w_buf, k, goff);
            float* t = Tcur; Tcur = Tprev; Tprev = t;
        }
    }
}